// Round 11
// baseline (435.294 us; speedup 1.0000x reference)
//
#include <hip/hip_runtime.h>

#define N_NODES 100000
#define N_HE    30000
#define N_INC   300000
#define NTOT    (N_HE + N_NODES)   // combined scan length
#define HEPAD   30080           // 235 * 128  (GEMM M-dim padding)
#define NREP    16              // BN-stat atomic replicas

typedef short  short8  __attribute__((ext_vector_type(8)));
typedef float  floatx4 __attribute__((ext_vector_type(4)));
typedef unsigned int uintx4 __attribute__((ext_vector_type(4)));

__device__ inline unsigned short f2bf(float f) {
  unsigned int u = __float_as_uint(f);
  u = (u + 0x7fff + ((u >> 16) & 1)) >> 16;   // round-to-nearest-even
  return (unsigned short)u;
}
__device__ inline unsigned int pack2(float lo, float hi) {
  return (unsigned int)f2bf(lo) | ((unsigned int)f2bf(hi) << 16);
}
__device__ inline void acc8(uint4 rv, float* a) {
  unsigned int u;
  u = rv.x; a[0] += __uint_as_float(u << 16); a[1] += __uint_as_float(u & 0xffff0000u);
  u = rv.y; a[2] += __uint_as_float(u << 16); a[3] += __uint_as_float(u & 0xffff0000u);
  u = rv.z; a[4] += __uint_as_float(u << 16); a[5] += __uint_as_float(u & 0xffff0000u);
  u = rv.w; a[6] += __uint_as_float(u << 16); a[7] += __uint_as_float(u & 0xffff0000u);
}

struct R4 { uint4 r[4]; };
struct R8 { uint4 r[8]; };

__device__ inline void load4(const unsigned short* __restrict__ base, const int* e,
                             int F, int c0, R4& o) {
#pragma unroll
  for (int k = 0; k < 4; k++)
    o.r[k] = *(const uint4*)(base + (size_t)e[k] * F + c0);
}
__device__ inline void accm4(const R4& o, int d, float* a) {
  if (d > 0) acc8(o.r[0], a);
  if (d > 1) acc8(o.r[1], a);
  if (d > 2) acc8(o.r[2], a);
  if (d > 3) acc8(o.r[3], a);
}
__device__ inline void load8(const unsigned short* __restrict__ base, const int* e,
                             int F, int c0, R8& o) {
#pragma unroll
  for (int k = 0; k < 8; k++)
    o.r[k] = *(const uint4*)(base + (size_t)e[k] * F + c0);
}
__device__ inline void accm8(const R8& o, int d, float* a) {
  acc8(o.r[0], a);
  if (d > 1) acc8(o.r[1], a);
  if (d > 2) acc8(o.r[2], a);
  if (d > 3) acc8(o.r[3], a);
  if (d > 4) acc8(o.r[4], a);
  if (d > 5) acc8(o.r[5], a);
  if (d > 6) acc8(o.r[6], a);
  if (d > 7) acc8(o.r[7], a);
}

// Pipelined 8-deep segment gather (deg~10 hyperedge side).
__device__ inline void gather8p(const unsigned short* __restrict__ base,
                                const int* __restrict__ idx, int beg, int end,
                                int F, int c0, float* a) {
  if (beg >= end) return;
  int e[8];
#pragma unroll
  for (int k = 0; k < 8; k++) e[k] = idx[min(beg + k, end - 1)];
  for (int j = beg; j < end; j += 8) {
    R8 r;
    load8(base, e, F, c0, r);
    int jn = j + 8;
    if (jn < end) {
#pragma unroll
      for (int k = 0; k < 8; k++) e[k] = idx[min(jn + k, end - 1)];
    }
    __builtin_amdgcn_sched_barrier(0);   // all loads issued before any consume
    accm8(r, end - j, a);
  }
}

// ---------------------------------------------------------------- CSR build + convert + fold_w1 (fused)

// Blocks [0, nconv): count incidences AND convert x to bf16.
// Blocks [nconv, nconv+8): fold W1 -> bf16 W1T (identity BN, cvec contribution
// is zero so no atomic needed; c1 stays memset-zero).
__global__ void count_convert(const int* __restrict__ nidx, const int* __restrict__ hidx,
                              int* __restrict__ cnt /* [he | node] */,
                              const float* __restrict__ x, unsigned short* __restrict__ xb,
                              const float* __restrict__ W1, unsigned short* __restrict__ W1T,
                              int nconv) {
  int bid = blockIdx.x;
  if (bid >= nconv) {
    int k0 = (bid - nconv) * 16;          // K=128 -> 8 blocks
    int n = threadIdx.x;                  // N=256
    unsigned short loc[16];
#pragma unroll
    for (int i = 0; i < 16; i++) loc[i] = f2bf(W1[(size_t)(k0 + i) * 256 + n]);
    *(uint4*)(W1T + (size_t)n * 128 + k0)     = *(const uint4*)&loc[0];
    *(uint4*)(W1T + (size_t)n * 128 + k0 + 8) = *(const uint4*)&loc[8];
    return;
  }
  int i = bid * 256 + threadIdx.x;
  if (i < N_INC) {
    atomicAdd(&cnt[N_HE + nidx[i]], 1);
    atomicAdd(&cnt[hidx[i]], 1);
  }
  if (i < N_NODES * 16) {
    const float4* p = (const float4*)x + (size_t)i * 2;
    float4 a = p[0], b = p[1];
    uint4 o;
    o.x = pack2(a.x, a.y); o.y = pack2(a.z, a.w);
    o.z = pack2(b.x, b.y); o.w = pack2(b.z, b.w);
    *(uint4*)(xb + (size_t)i * 8) = o;
  }
}

__global__ void scan1(const int* __restrict__ cnt, int* __restrict__ incl,
                      int* __restrict__ bsums, int n) {
  __shared__ int tmp[1024];
  int tid = threadIdx.x;
  int i = blockIdx.x * 1024 + tid;
  tmp[tid] = (i < n) ? cnt[i] : 0;
  __syncthreads();
  for (int off = 1; off < 1024; off <<= 1) {
    int t = (tid >= off) ? tmp[tid - off] : 0;
    __syncthreads();
    tmp[tid] += t;
    __syncthreads();
  }
  if (i < n) incl[i] = tmp[tid];
  if (tid == 1023) bsums[blockIdx.x] = tmp[1023];
}

// Parallel exclusive scan over block sums (nb <= 128).
__global__ void scan2(int* __restrict__ bsums, int nb) {
  __shared__ int tmp[128];
  int t = threadIdx.x;
  int my = (t < nb) ? bsums[t] : 0;
  tmp[t] = my;
  __syncthreads();
  for (int off = 1; off < 128; off <<= 1) {
    int v = (t >= off) ? tmp[t - off] : 0;
    __syncthreads();
    tmp[t] += v;
    __syncthreads();
  }
  if (t < nb) bsums[t] = tmp[t] - my;   // exclusive
}

// Combined scan3: i < N_HE -> he side; else node side (prefix - N_INC, since
// the hyperedge counts sum to exactly N_INC).
__global__ void scan3c(const int* __restrict__ cnt, const int* __restrict__ incl,
                       const int* __restrict__ bsums,
                       int* __restrict__ he_ptr, int* __restrict__ he_fill,
                       int* __restrict__ node_ptr, int* __restrict__ node_fill) {
  int i = blockIdx.x * 1024 + threadIdx.x;
  if (i >= NTOT) return;
  int e = incl[i] - cnt[i] + bsums[blockIdx.x];
  if (i < N_HE) {
    he_ptr[i] = e;
    he_fill[i] = e;
    if (i == N_HE - 1) he_ptr[N_HE] = N_INC;
  } else {
    int v = e - N_INC;
    node_ptr[i - N_HE] = v;
    node_fill[i - N_HE] = v;
    if (i == NTOT - 1) node_ptr[N_NODES] = N_INC;
  }
}

__global__ void fill_kernel(const int* __restrict__ nidx, const int* __restrict__ hidx,
                            int* __restrict__ node_fill, int* __restrict__ he_fill,
                            int* __restrict__ node_hes, int* __restrict__ he_nodes) {
  int i = blockIdx.x * blockDim.x + threadIdx.x;
  if (i < N_INC) {
    int nn = nidx[i], hh = hidx[i];
    int p1 = atomicAdd(&node_fill[nn], 1);
    node_hes[p1] = hh;
    int p2 = atomicAdd(&he_fill[hh], 1);
    he_nodes[p2] = nn;
  }
}

// ---------------------------------------------------------------- weight fold

// Fused BN-finalize + weight fold (layers 2/3; runs on side stream s2,
// overlapped with the same layer's agg_he on the main stream).
// gsum/gss are NREP-replicated [NREP][256] partial sums.
__global__ __launch_bounds__(256) void fold_w(
    const float* __restrict__ W, const float* __restrict__ gsum,
    const float* __restrict__ gss, const float* __restrict__ g,
    const float* __restrict__ be, unsigned short* __restrict__ WT,
    float* __restrict__ cvec, int K, int N, float invN) {
  int n = blockIdx.y * 256 + threadIdx.x;
  if (n >= N) return;
  int k0 = blockIdx.x * 16;
  float c = 0.f;
  unsigned short loc[16];
#pragma unroll
  for (int i = 0; i < 16; i++) {
    int k = k0 + i;
    float w = W[(size_t)k * N + n];
    float ms = 0.f, vs = 0.f;
#pragma unroll
    for (int r = 0; r < NREP; r++) { ms += gsum[r * 256 + k]; vs += gss[r * 256 + k]; }
    float m = ms * invN;
    float v = vs * invN - m * m;
    float s = g[k] * rsqrtf(v + 1e-5f);
    float t = be[k] - m * s;
    loc[i] = f2bf(w * s);
    c += t * w;
  }
  *(uint4*)(WT + (size_t)n * K + k0)     = *(const uint4*)&loc[0];
  *(uint4*)(WT + (size_t)n * K + k0 + 8) = *(const uint4*)&loc[8];
  atomicAdd(cvec + n, c);
}

// ---------------------------------------------------------------- bf16 MFMA GEMM (m97 pattern)

__global__ __launch_bounds__(256) void gemm_mfma(
    const unsigned short* __restrict__ A, const unsigned short* __restrict__ BT,
    unsigned short* __restrict__ C, int K, int N) {
  __shared__ unsigned short As[128 * 32];
  __shared__ unsigned short Bs[128 * 32];
  const int tid  = threadIdx.x;
  const int w    = tid >> 6, lane = tid & 63;
  const int wm   = w & 1,  wn   = w >> 1;
  const int bm   = blockIdx.x * 128, bn = blockIdx.y * 128;
  const int quad = lane >> 4, r16 = lane & 15;

  floatx4 acc[4][4] = {};

  const int srow = (lane >> 2);
  const int scol = (lane & 3) * 8;

  for (int kb = 0; kb < K; kb += 32) {
#pragma unroll
    for (int i = 0; i < 2; i++) {
      const int row = (w * 2 + i) * 16 + srow;
      const unsigned short* ga = A  + (size_t)(bm + row) * K + kb + scol;
      const unsigned short* gb = BT + (size_t)(bn + row) * K + kb + scol;
      __builtin_amdgcn_global_load_lds(
          (const __attribute__((address_space(1))) void*)ga,
          (__attribute__((address_space(3))) void*)(&As[(w * 2 + i) * 512]), 16, 0, 0);
      __builtin_amdgcn_global_load_lds(
          (const __attribute__((address_space(1))) void*)gb,
          (__attribute__((address_space(3))) void*)(&Bs[(w * 2 + i) * 512]), 16, 0, 0);
    }
    __syncthreads();
    short8 af[4], bfr[4];
#pragma unroll
    for (int t = 0; t < 4; t++) {
      af[t]  = *(const short8*)&As[(wm * 64 + t * 16 + r16) * 32 + quad * 8];
      bfr[t] = *(const short8*)&Bs[(wn * 64 + t * 16 + r16) * 32 + quad * 8];
    }
#pragma unroll
    for (int mi = 0; mi < 4; mi++)
#pragma unroll
      for (int ni = 0; ni < 4; ni++)
        acc[mi][ni] = __builtin_amdgcn_mfma_f32_16x16x32_bf16(af[mi], bfr[ni], acc[mi][ni], 0, 0, 0);
    __syncthreads();
  }
#pragma unroll
  for (int mi = 0; mi < 4; mi++)
#pragma unroll
    for (int ni = 0; ni < 4; ni++)
#pragma unroll
      for (int rr = 0; rr < 4; rr++) {
        int gm = bm + wm * 64 + mi * 16 + quad * 4 + rr;
        int gn = bn + wn * 64 + ni * 16 + r16;
        C[(size_t)gm * N + gn] = f2bf(acc[mi][ni][rr]);
      }
}

// ---------------------------------------------------------------- aggregations (bf16 in/out)

// node -> hyperedge mean (deg~10). F/8 lanes per segment; shift=log2(F/8).
__global__ __launch_bounds__(256, 4) void agg_he(
    const unsigned short* __restrict__ src, const int* __restrict__ ptr,
    const int* __restrict__ idx, unsigned short* __restrict__ dst,
    int F, int shift, int nSeg) {
  int seg = blockIdx.x * (256 >> shift) + (threadIdx.x >> shift);
  if (seg >= nSeg) return;
  int l = threadIdx.x & ((1 << shift) - 1);
  int c0 = l * 8;
  int beg = ptr[seg], end = ptr[seg + 1];
  float a[8] = {};
  gather8p(src, idx, beg, end, F, c0, a);
  float inv = (end > beg) ? 1.0f / (float)(end - beg) : 0.0f;
  uint4 o;
  o.x = pack2(a[0] * inv, a[1] * inv);
  o.y = pack2(a[2] * inv, a[3] * inv);
  o.z = pack2(a[4] * inv, a[5] * inv);
  o.w = pack2(a[6] * inv, a[7] * inv);
  *(uint4*)(dst + (size_t)seg * F + c0) = o;
}

// hyperedge -> node, F=256, CHANNEL-QUARTERED + XCD-PINNED.
// Workgroups round-robin across the 8 XCDs by blockIdx, so quarter =
// (bid&7)>>1 pins each XCD's L2 to ONE 3.85 MB slice of HEb — which fits
// the 4 MB per-XCD L2 entirely (round-7: FETCH 47->22 MB confirmed).
// nt-store on dst (Bb) is kept: with pinning, a regular store would
// write-allocate 6.4 MB/XCD of Bb through the 4 MB L2 and evict the
// pinned HEb slice (r3's "regular wins" predates pinning).
__global__ __launch_bounds__(256, 4) void node_agg_bn(
    const unsigned short* __restrict__ he, const int* __restrict__ nptr,
    const int* __restrict__ nhes, const float* __restrict__ b,
    const float* __restrict__ cvec, unsigned short* __restrict__ dst,
    float* __restrict__ gsum, float* __restrict__ gss) {
  const int F = 256;
  const int bid = blockIdx.x;
  const int qi = (bid & 7) >> 1;                // channel quarter, pinned per XCD pair
  const int xb = (bid >> 3) * 2 + (bid & 1);    // node-block within quarter
  const int grp = threadIdx.x >> 3;             // 32 groups
  const int l   = threadIdx.x & 7;
  const int c0  = qi * 64 + l * 8;              // global channel base
  float bb[8], cc[8];
#pragma unroll
  for (int j = 0; j < 8; j++) { bb[j] = b[c0 + j]; cc[j] = cvec[c0 + j]; }
  const int base_n = xb * 128 + grp * 4;
  int begs[4], ends[4];
#pragma unroll
  for (int i = 0; i < 4; i++) {
    int n = base_n + i;
    begs[i] = (n < N_NODES) ? nptr[n] : 0;
    ends[i] = (n < N_NODES) ? nptr[n + 1] : 0;
  }
  int e[4][4];
#pragma unroll
  for (int i = 0; i < 4; i++) {
#pragma unroll
    for (int k = 0; k < 4; k++)
      e[i][k] = (begs[i] < ends[i]) ? nhes[min(begs[i] + k, ends[i] - 1)] : 0;
  }
  R4 r0, r1, r2, r3;                            // 16 row loads in flight
  load4(he, e[0], F, c0, r0);
  load4(he, e[1], F, c0, r1);
  load4(he, e[2], F, c0, r2);
  load4(he, e[3], F, c0, r3);
  __builtin_amdgcn_sched_barrier(0);            // pin: issue all before consume
  float sb[8] = {}, ssb[8] = {};
#pragma unroll
  for (int t = 0; t < 4; t++) {
    const int d = ends[t] - begs[t];
    float a[8] = {};
    const R4& rr = (t == 0) ? r0 : (t == 1) ? r1 : (t == 2) ? r2 : r3;
    accm4(rr, d, a);
    for (int j = begs[t] + 4; j < ends[t]; j += 4) {   // tail deg>4 (rare)
      int et[4];
#pragma unroll
      for (int k = 0; k < 4; k++) et[k] = nhes[min(j + k, ends[t] - 1)];
      R4 tt; load4(he, et, F, c0, tt);
      accm4(tt, ends[t] - j, a);
    }
    const int n = base_n + t;
    if (n < N_NODES) {
      float inv  = (d > 0) ? 1.0f / (float)d : 0.0f;
      float cmul = (d > 0) ? 1.0f : 0.0f;       // deg-0 node: +b only
      float o[8];
#pragma unroll
      for (int j = 0; j < 8; j++) {
        o[j] = fmaxf(fmaf(a[j], inv, bb[j] + cmul * cc[j]), 0.f);
        sb[j] += o[j]; ssb[j] += o[j] * o[j];
      }
      uintx4 ov;
      ov.x = pack2(o[0], o[1]); ov.y = pack2(o[2], o[3]);
      ov.z = pack2(o[4], o[5]); ov.w = pack2(o[6], o[7]);
      __builtin_nontemporal_store(ov, (uintx4*)(dst + (size_t)n * F + c0));
    }
  }
  __shared__ float Ls[32][64];
  __shared__ float Lss[32][64];
#pragma unroll
  for (int j = 0; j < 8; j++) { Ls[grp][l * 8 + j] = sb[j]; Lss[grp][l * 8 + j] = ssb[j]; }
  __syncthreads();
  if (threadIdx.x < 64) {
    int c = threadIdx.x;
    float a1 = 0.f, a2 = 0.f;
#pragma unroll
    for (int h = 0; h < 32; h++) { a1 += Ls[h][c]; a2 += Lss[h][c]; }
    const int rep = xb & (NREP - 1);
    atomicAdd(gsum + rep * 256 + qi * 64 + c, a1);
    atomicAdd(gss  + rep * 256 + qi * 64 + c, a2);
  }
}

// final hyperedge -> node, F=128, CHANNEL-HALVED + XCD-PINNED: half =
// (bid&7)>>2 -> each XCD pinned to one 3.85 MB half of HEb3 (fits L2).
__global__ __launch_bounds__(256, 4) void agg_out(
    const unsigned short* __restrict__ he, const int* __restrict__ nptr,
    const int* __restrict__ nhes, const float* __restrict__ b,
    const float* __restrict__ cvec, float* __restrict__ out) {
  const int F = 128;
  const int bid = blockIdx.x;
  const int hi = (bid & 7) >> 2;                // channel half, pinned per XCD quad
  const int xb = (bid >> 3) * 4 + (bid & 3);    // node-block within half
  const int grp = threadIdx.x >> 3;
  const int l   = threadIdx.x & 7;
  const int c0  = hi * 64 + l * 8;
  float bb[8], cc[8];
#pragma unroll
  for (int j = 0; j < 8; j++) { bb[j] = b[c0 + j]; cc[j] = cvec[c0 + j]; }
  const int base_n = xb * 128 + grp * 4;
  int begs[4], ends[4];
#pragma unroll
  for (int i = 0; i < 4; i++) {
    int n = base_n + i;
    begs[i] = (n < N_NODES) ? nptr[n] : 0;
    ends[i] = (n < N_NODES) ? nptr[n + 1] : 0;
  }
  int e[4][4];
#pragma unroll
  for (int i = 0; i < 4; i++) {
#pragma unroll
    for (int k = 0; k < 4; k++)
      e[i][k] = (begs[i] < ends[i]) ? nhes[min(begs[i] + k, ends[i] - 1)] : 0;
  }
  R4 r0, r1, r2, r3;
  load4(he, e[0], F, c0, r0);
  load4(he, e[1], F, c0, r1);
  load4(he, e[2], F, c0, r2);
  load4(he, e[3], F, c0, r3);
  __builtin_amdgcn_sched_barrier(0);            // pin: issue all before consume
#pragma unroll
  for (int t = 0; t < 4; t++) {
    const int d = ends[t] - begs[t];
    float a[8] = {};
    const R4& rr = (t == 0) ? r0 : (t == 1) ? r1 : (t == 2) ? r2 : r3;
    accm4(rr, d, a);
    for (int j = begs[t] + 4; j < ends[t]; j += 4) {
      int et[4];
#pragma unroll
      for (int k = 0; k < 4; k++) et[k] = nhes[min(j + k, ends[t] - 1)];
      R4 tt; load4(he, et, F, c0, tt);
      accm4(tt, ends[t] - j, a);
    }
    const int n = base_n + t;
    if (n < N_NODES) {
      float inv  = (d > 0) ? 1.0f / (float)d : 0.0f;
      float cmul = (d > 0) ? 1.0f : 0.0f;
      floatx4 o0, o1;
#pragma unroll
      for (int j = 0; j < 4; j++)
        o0[j] = fmaxf(fmaf(a[j], inv, bb[j] + cmul * cc[j]), 0.f);
#pragma unroll
      for (int j = 0; j < 4; j++)
        o1[j] = fmaxf(fmaf(a[4 + j], inv, bb[4 + j] + cmul * cc[4 + j]), 0.f);
      float* dp = out + (size_t)n * F + c0;
      __builtin_nontemporal_store(o0, (floatx4*)dp);
      __builtin_nontemporal_store(o1, (floatx4*)(dp + 4));
    }
  }
}

// ---------------------------------------------------------------- launch

extern "C" void kernel_launch(void* const* d_in, const int* in_sizes, int n_in,
                              void* d_out, int out_size, void* d_ws, size_t ws_size,
                              hipStream_t stream) {
  const float* x    = (const float*)d_in[0];
  const int*   edge = (const int*)d_in[1];
  const int*   nidx = edge;
  const int*   hidx = edge + N_INC;
  const float* W1  = (const float*)d_in[2];
  const float* b1  = (const float*)d_in[3];
  const float* g1  = (const float*)d_in[4];
  const float* be1 = (const float*)d_in[5];
  const float* W2  = (const float*)d_in[6];
  const float* b2  = (const float*)d_in[7];
  const float* g2  = (const float*)d_in[8];
  const float* be2 = (const float*)d_in[9];
  const float* W3  = (const float*)d_in[10];
  const float* b3  = (const float*)d_in[11];
  float* out = (float*)d_out;

  // Side stream + fork/join events (created once; host-side APIs, capture-legal).
  static hipStream_t s2 = nullptr;
  static hipEvent_t evF2 = nullptr, evJ2 = nullptr, evF3 = nullptr, evJ3 = nullptr;
  if (s2 == nullptr) {
    (void)hipStreamCreateWithFlags(&s2, hipStreamNonBlocking);
    (void)hipEventCreateWithFlags(&evF2, hipEventDisableTiming);
    (void)hipEventCreateWithFlags(&evJ2, hipEventDisableTiming);
    (void)hipEventCreateWithFlags(&evF3, hipEventDisableTiming);
    (void)hipEventCreateWithFlags(&evJ3, hipEventDisableTiming);
  }

  char* ws = (char*)d_ws;
  size_t off = 0;
  auto alloc = [&](size_t bytes) -> void* {
    void* p = ws + off;
    off = (off + bytes + 255) & ~(size_t)255;
    return p;
  };
  unsigned short* Xb   = (unsigned short*)alloc((size_t)N_NODES * 128 * 2);
  unsigned short* Bb   = (unsigned short*)alloc((size_t)N_NODES * 256 * 2);
  unsigned short* Hraw = (unsigned short*)alloc((size_t)HEPAD * 256 * 2);
  unsigned short* HEb  = (unsigned short*)alloc((size_t)HEPAD * 256 * 2);
  unsigned short* W1T  = (unsigned short*)alloc((size_t)256 * 128 * 2);
  unsigned short* W2T  = (unsigned short*)alloc((size_t)256 * 256 * 2);
  unsigned short* W3T  = (unsigned short*)alloc((size_t)128 * 256 * 2);
  size_t zero_begin = off;
  int* cnt = (int*)alloc((size_t)NTOT * 4);       // [he_cnt | node_cnt] contiguous
  float* gsum1 = (float*)alloc((size_t)NREP * 256 * 4);
  float* gss1  = (float*)alloc((size_t)NREP * 256 * 4);
  float* gsum2 = (float*)alloc((size_t)NREP * 256 * 4);
  float* gss2  = (float*)alloc((size_t)NREP * 256 * 4);
  float* c1 = (float*)alloc(1024);
  float* c2 = (float*)alloc(1024);
  float* c3 = (float*)alloc(1024);
  size_t zero_end = off;
  int* he_ptr    = (int*)alloc((size_t)(N_HE + 1) * 4);
  int* node_ptr  = (int*)alloc((size_t)(N_NODES + 1) * 4);
  int* he_fill   = (int*)alloc((size_t)N_HE * 4);
  int* node_fill = (int*)alloc((size_t)N_NODES * 4);
  int* he_nodes  = (int*)alloc((size_t)N_INC * 4);
  int* node_hes  = (int*)alloc((size_t)N_INC * 4);
  int* incl      = (int*)alloc((size_t)NTOT * 4);
  int* bsums     = (int*)alloc(512);

  // ---- zero counters/accumulators (single async memset) ----
  hipMemsetAsync((void*)(ws + zero_begin), 0, zero_end - zero_begin, stream);

  // ---- CSR build (combined scan) + x conversion + W1 fold (all fused) ----
  const int NCONV = (N_NODES * 16) / 256;   // 6250
  count_convert<<<NCONV + 8, 256, 0, stream>>>(nidx, hidx, cnt, x, Xb, W1, W1T, NCONV);
  {
    int nb = (NTOT + 1023) / 1024;      // 127
    scan1<<<nb, 1024, 0, stream>>>(cnt, incl, bsums, NTOT);
    scan2<<<1, 128, 0, stream>>>(bsums, nb);
    scan3c<<<nb, 1024, 0, stream>>>(cnt, incl, bsums, he_ptr, he_fill, node_ptr, node_fill);
  }
  fill_kernel<<<(N_INC + 255) / 256, 256, 0, stream>>>(nidx, hidx, node_fill, he_fill,
                                                       node_hes, he_nodes);

  const int MBHE = HEPAD / 128;         // 235
  const int QB = (N_NODES + 127) / 128; // 782 node-blocks (even)
  const int GRID_NA = 8 * ((QB + 1) / 2);   // 4 quarters x 2 XCDs each
  const int GRID_AO = 8 * ((QB + 3) / 4);   // 2 halves x 4 XCDs each
  const float invN = 1.0f / (float)N_NODES;

  // ---- layer 1 ----
  agg_he<<<(N_HE + 15) / 16, 256, 0, stream>>>(Xb, he_ptr, he_nodes, Hraw, 128, 4, N_HE);
  { dim3 g(MBHE, 2); gemm_mfma<<<g, 256, 0, stream>>>(Hraw, W1T, HEb, 128, 256); }
  node_agg_bn<<<GRID_NA, 256, 0, stream>>>(HEb, node_ptr, node_hes, b1, c1,
                                           Bb, gsum1, gss1);

  // ---- layer 2: fold_w2 (s2) overlapped with agg_he2 (main) ----
  (void)hipEventRecord(evF2, stream);
  (void)hipStreamWaitEvent(s2, evF2, 0);
  { dim3 g(256 / 16, 1);
    fold_w<<<g, 256, 0, s2>>>(W2, gsum1, gss1, g1, be1, W2T, c2, 256, 256, invN); }
  agg_he<<<(N_HE + 7) / 8, 256, 0, stream>>>(Bb, he_ptr, he_nodes, Hraw, 256, 5, N_HE);
  (void)hipEventRecord(evJ2, s2);
  (void)hipStreamWaitEvent(stream, evJ2, 0);
  { dim3 g(MBHE, 2); gemm_mfma<<<g, 256, 0, stream>>>(Hraw, W2T, HEb, 256, 256); }
  node_agg_bn<<<GRID_NA, 256, 0, stream>>>(HEb, node_ptr, node_hes, b2, c2,
                                           Bb, gsum2, gss2);

  // ---- layer 3: fold_w3 (s2) overlapped with agg_he3 (main) ----
  (void)hipEventRecord(evF3, stream);
  (void)hipStreamWaitEvent(s2, evF3, 0);
  { dim3 g(256 / 16, 1);
    fold_w<<<g, 256, 0, s2>>>(W3, gsum2, gss2, g2, be2, W3T, c3, 256, 128, invN); }
  agg_he<<<(N_HE + 7) / 8, 256, 0, stream>>>(Bb, he_ptr, he_nodes, Hraw, 256, 5, N_HE);
  (void)hipEventRecord(evJ3, s2);
  (void)hipStreamWaitEvent(stream, evJ3, 0);
  { dim3 g(MBHE, 1); gemm_mfma<<<g, 256, 0, stream>>>(Hraw, W3T, HEb, 256, 128); }
  agg_out<<<GRID_AO, 256, 0, stream>>>(HEb, node_ptr, node_hes, b3, c3, out);
}

// Round 12
// 400.041 us; speedup vs baseline: 1.0881x; 1.0881x over previous
//
#include <hip/hip_runtime.h>

#define N_NODES 100000
#define N_HE    30000
#define N_INC   300000
#define NTOT    (N_HE + N_NODES)   // combined scan length
#define HEPAD   30080           // 235 * 128  (GEMM M-dim padding)
#define NREP    16              // BN-stat atomic replicas

typedef short  short8  __attribute__((ext_vector_type(8)));
typedef float  floatx4 __attribute__((ext_vector_type(4)));
typedef unsigned int uintx4 __attribute__((ext_vector_type(4)));

__device__ inline unsigned short f2bf(float f) {
  unsigned int u = __float_as_uint(f);
  u = (u + 0x7fff + ((u >> 16) & 1)) >> 16;   // round-to-nearest-even
  return (unsigned short)u;
}
__device__ inline unsigned int pack2(float lo, float hi) {
  return (unsigned int)f2bf(lo) | ((unsigned int)f2bf(hi) << 16);
}
__device__ inline void acc8(uint4 rv, float* a) {
  unsigned int u;
  u = rv.x; a[0] += __uint_as_float(u << 16); a[1] += __uint_as_float(u & 0xffff0000u);
  u = rv.y; a[2] += __uint_as_float(u << 16); a[3] += __uint_as_float(u & 0xffff0000u);
  u = rv.z; a[4] += __uint_as_float(u << 16); a[5] += __uint_as_float(u & 0xffff0000u);
  u = rv.w; a[6] += __uint_as_float(u << 16); a[7] += __uint_as_float(u & 0xffff0000u);
}

struct R4 { uint4 r[4]; };
struct R8 { uint4 r[8]; };

__device__ inline void load4(const unsigned short* __restrict__ base, const int* e,
                             int F, int c0, R4& o) {
#pragma unroll
  for (int k = 0; k < 4; k++)
    o.r[k] = *(const uint4*)(base + (size_t)e[k] * F + c0);
}
__device__ inline void accm4(const R4& o, int d, float* a) {
  if (d > 0) acc8(o.r[0], a);
  if (d > 1) acc8(o.r[1], a);
  if (d > 2) acc8(o.r[2], a);
  if (d > 3) acc8(o.r[3], a);
}
__device__ inline void load8(const unsigned short* __restrict__ base, const int* e,
                             int F, int c0, R8& o) {
#pragma unroll
  for (int k = 0; k < 8; k++)
    o.r[k] = *(const uint4*)(base + (size_t)e[k] * F + c0);
}
__device__ inline void accm8(const R8& o, int d, float* a) {
  acc8(o.r[0], a);
  if (d > 1) acc8(o.r[1], a);
  if (d > 2) acc8(o.r[2], a);
  if (d > 3) acc8(o.r[3], a);
  if (d > 4) acc8(o.r[4], a);
  if (d > 5) acc8(o.r[5], a);
  if (d > 6) acc8(o.r[6], a);
  if (d > 7) acc8(o.r[7], a);
}

// Pipelined 8-deep segment gather (deg~10 hyperedge side).
__device__ inline void gather8p(const unsigned short* __restrict__ base,
                                const int* __restrict__ idx, int beg, int end,
                                int F, int c0, float* a) {
  if (beg >= end) return;
  int e[8];
#pragma unroll
  for (int k = 0; k < 8; k++) e[k] = idx[min(beg + k, end - 1)];
  for (int j = beg; j < end; j += 8) {
    R8 r;
    load8(base, e, F, c0, r);
    int jn = j + 8;
    if (jn < end) {
#pragma unroll
      for (int k = 0; k < 8; k++) e[k] = idx[min(jn + k, end - 1)];
    }
    __builtin_amdgcn_sched_barrier(0);   // all loads issued before any consume
    accm8(r, end - j, a);
  }
}

// ---------------------------------------------------------------- CSR build + convert + fold_w1 (fused)

// Blocks [0, nconv): count incidences AND convert x to bf16.
// Blocks [nconv, nconv+8): fold W1 -> bf16 W1T (identity BN, cvec contribution
// is zero so no atomic needed; c1 stays memset-zero).
__global__ void count_convert(const int* __restrict__ nidx, const int* __restrict__ hidx,
                              int* __restrict__ cnt /* [he | node] */,
                              const float* __restrict__ x, unsigned short* __restrict__ xb,
                              const float* __restrict__ W1, unsigned short* __restrict__ W1T,
                              int nconv) {
  int bid = blockIdx.x;
  if (bid >= nconv) {
    int k0 = (bid - nconv) * 16;          // K=128 -> 8 blocks
    int n = threadIdx.x;                  // N=256
    unsigned short loc[16];
#pragma unroll
    for (int i = 0; i < 16; i++) loc[i] = f2bf(W1[(size_t)(k0 + i) * 256 + n]);
    *(uint4*)(W1T + (size_t)n * 128 + k0)     = *(const uint4*)&loc[0];
    *(uint4*)(W1T + (size_t)n * 128 + k0 + 8) = *(const uint4*)&loc[8];
    return;
  }
  int i = bid * 256 + threadIdx.x;
  if (i < N_INC) {
    atomicAdd(&cnt[N_HE + nidx[i]], 1);
    atomicAdd(&cnt[hidx[i]], 1);
  }
  if (i < N_NODES * 16) {
    const float4* p = (const float4*)x + (size_t)i * 2;
    float4 a = p[0], b = p[1];
    uint4 o;
    o.x = pack2(a.x, a.y); o.y = pack2(a.z, a.w);
    o.z = pack2(b.x, b.y); o.w = pack2(b.z, b.w);
    *(uint4*)(xb + (size_t)i * 8) = o;
  }
}

__global__ void scan1(const int* __restrict__ cnt, int* __restrict__ incl,
                      int* __restrict__ bsums, int n) {
  __shared__ int tmp[1024];
  int tid = threadIdx.x;
  int i = blockIdx.x * 1024 + tid;
  tmp[tid] = (i < n) ? cnt[i] : 0;
  __syncthreads();
  for (int off = 1; off < 1024; off <<= 1) {
    int t = (tid >= off) ? tmp[tid - off] : 0;
    __syncthreads();
    tmp[tid] += t;
    __syncthreads();
  }
  if (i < n) incl[i] = tmp[tid];
  if (tid == 1023) bsums[blockIdx.x] = tmp[1023];
}

// Parallel exclusive scan over block sums (nb <= 128).
__global__ void scan2(int* __restrict__ bsums, int nb) {
  __shared__ int tmp[128];
  int t = threadIdx.x;
  int my = (t < nb) ? bsums[t] : 0;
  tmp[t] = my;
  __syncthreads();
  for (int off = 1; off < 128; off <<= 1) {
    int v = (t >= off) ? tmp[t - off] : 0;
    __syncthreads();
    tmp[t] += v;
    __syncthreads();
  }
  if (t < nb) bsums[t] = tmp[t] - my;   // exclusive
}

// Combined scan3: i < N_HE -> he side; else node side (prefix - N_INC, since
// the hyperedge counts sum to exactly N_INC).
__global__ void scan3c(const int* __restrict__ cnt, const int* __restrict__ incl,
                       const int* __restrict__ bsums,
                       int* __restrict__ he_ptr, int* __restrict__ he_fill,
                       int* __restrict__ node_ptr, int* __restrict__ node_fill) {
  int i = blockIdx.x * 1024 + threadIdx.x;
  if (i >= NTOT) return;
  int e = incl[i] - cnt[i] + bsums[blockIdx.x];
  if (i < N_HE) {
    he_ptr[i] = e;
    he_fill[i] = e;
    if (i == N_HE - 1) he_ptr[N_HE] = N_INC;
  } else {
    int v = e - N_INC;
    node_ptr[i - N_HE] = v;
    node_fill[i - N_HE] = v;
    if (i == NTOT - 1) node_ptr[N_NODES] = N_INC;
  }
}

__global__ void fill_kernel(const int* __restrict__ nidx, const int* __restrict__ hidx,
                            int* __restrict__ node_fill, int* __restrict__ he_fill,
                            int* __restrict__ node_hes, int* __restrict__ he_nodes) {
  int i = blockIdx.x * blockDim.x + threadIdx.x;
  if (i < N_INC) {
    int nn = nidx[i], hh = hidx[i];
    int p1 = atomicAdd(&node_fill[nn], 1);
    node_hes[p1] = hh;
    int p2 = atomicAdd(&he_fill[hh], 1);
    he_nodes[p2] = nn;
  }
}

// ---------------------------------------------------------------- weight fold

// Fused BN-finalize + weight fold (layers 2/3).
// gsum/gss are NREP-replicated [NREP][256] partial sums.
__global__ __launch_bounds__(256) void fold_w(
    const float* __restrict__ W, const float* __restrict__ gsum,
    const float* __restrict__ gss, const float* __restrict__ g,
    const float* __restrict__ be, unsigned short* __restrict__ WT,
    float* __restrict__ cvec, int K, int N, float invN) {
  int n = blockIdx.y * 256 + threadIdx.x;
  if (n >= N) return;
  int k0 = blockIdx.x * 16;
  float c = 0.f;
  unsigned short loc[16];
#pragma unroll
  for (int i = 0; i < 16; i++) {
    int k = k0 + i;
    float w = W[(size_t)k * N + n];
    float ms = 0.f, vs = 0.f;
#pragma unroll
    for (int r = 0; r < NREP; r++) { ms += gsum[r * 256 + k]; vs += gss[r * 256 + k]; }
    float m = ms * invN;
    float v = vs * invN - m * m;
    float s = g[k] * rsqrtf(v + 1e-5f);
    float t = be[k] - m * s;
    loc[i] = f2bf(w * s);
    c += t * w;
  }
  *(uint4*)(WT + (size_t)n * K + k0)     = *(const uint4*)&loc[0];
  *(uint4*)(WT + (size_t)n * K + k0 + 8) = *(const uint4*)&loc[8];
  atomicAdd(cvec + n, c);
}

// ---------------------------------------------------------------- bf16 MFMA GEMM (m97 pattern)

__global__ __launch_bounds__(256) void gemm_mfma(
    const unsigned short* __restrict__ A, const unsigned short* __restrict__ BT,
    unsigned short* __restrict__ C, int K, int N) {
  __shared__ unsigned short As[128 * 32];
  __shared__ unsigned short Bs[128 * 32];
  const int tid  = threadIdx.x;
  const int w    = tid >> 6, lane = tid & 63;
  const int wm   = w & 1,  wn   = w >> 1;
  const int bm   = blockIdx.x * 128, bn = blockIdx.y * 128;
  const int quad = lane >> 4, r16 = lane & 15;

  floatx4 acc[4][4] = {};

  const int srow = (lane >> 2);
  const int scol = (lane & 3) * 8;

  for (int kb = 0; kb < K; kb += 32) {
#pragma unroll
    for (int i = 0; i < 2; i++) {
      const int row = (w * 2 + i) * 16 + srow;
      const unsigned short* ga = A  + (size_t)(bm + row) * K + kb + scol;
      const unsigned short* gb = BT + (size_t)(bn + row) * K + kb + scol;
      __builtin_amdgcn_global_load_lds(
          (const __attribute__((address_space(1))) void*)ga,
          (__attribute__((address_space(3))) void*)(&As[(w * 2 + i) * 512]), 16, 0, 0);
      __builtin_amdgcn_global_load_lds(
          (const __attribute__((address_space(1))) void*)gb,
          (__attribute__((address_space(3))) void*)(&Bs[(w * 2 + i) * 512]), 16, 0, 0);
    }
    __syncthreads();
    short8 af[4], bfr[4];
#pragma unroll
    for (int t = 0; t < 4; t++) {
      af[t]  = *(const short8*)&As[(wm * 64 + t * 16 + r16) * 32 + quad * 8];
      bfr[t] = *(const short8*)&Bs[(wn * 64 + t * 16 + r16) * 32 + quad * 8];
    }
#pragma unroll
    for (int mi = 0; mi < 4; mi++)
#pragma unroll
      for (int ni = 0; ni < 4; ni++)
        acc[mi][ni] = __builtin_amdgcn_mfma_f32_16x16x32_bf16(af[mi], bfr[ni], acc[mi][ni], 0, 0, 0);
    __syncthreads();
  }
#pragma unroll
  for (int mi = 0; mi < 4; mi++)
#pragma unroll
    for (int ni = 0; ni < 4; ni++)
#pragma unroll
      for (int rr = 0; rr < 4; rr++) {
        int gm = bm + wm * 64 + mi * 16 + quad * 4 + rr;
        int gn = bn + wn * 64 + ni * 16 + r16;
        C[(size_t)gm * N + gn] = f2bf(acc[mi][ni][rr]);
      }
}

// ---------------------------------------------------------------- aggregations (bf16 in/out)

// node -> hyperedge mean (deg~10). F/8 lanes per segment; shift=log2(F/8).
__global__ __launch_bounds__(256, 4) void agg_he(
    const unsigned short* __restrict__ src, const int* __restrict__ ptr,
    const int* __restrict__ idx, unsigned short* __restrict__ dst,
    int F, int shift, int nSeg) {
  int seg = blockIdx.x * (256 >> shift) + (threadIdx.x >> shift);
  if (seg >= nSeg) return;
  int l = threadIdx.x & ((1 << shift) - 1);
  int c0 = l * 8;
  int beg = ptr[seg], end = ptr[seg + 1];
  float a[8] = {};
  gather8p(src, idx, beg, end, F, c0, a);
  float inv = (end > beg) ? 1.0f / (float)(end - beg) : 0.0f;
  uint4 o;
  o.x = pack2(a[0] * inv, a[1] * inv);
  o.y = pack2(a[2] * inv, a[3] * inv);
  o.z = pack2(a[4] * inv, a[5] * inv);
  o.w = pack2(a[6] * inv, a[7] * inv);
  *(uint4*)(dst + (size_t)seg * F + c0) = o;
}

// hyperedge -> node, F=256, CHANNEL-QUARTERED + XCD-PINNED.
// Workgroups round-robin across the 8 XCDs by blockIdx, so quarter =
// (bid&7)>>1 pins each XCD's L2 to ONE 3.85 MB slice of HEb — which fits
// the 4 MB per-XCD L2 entirely (round-7: FETCH 47->22 MB confirmed).
__global__ __launch_bounds__(256, 4) void node_agg_bn(
    const unsigned short* __restrict__ he, const int* __restrict__ nptr,
    const int* __restrict__ nhes, const float* __restrict__ b,
    const float* __restrict__ cvec, unsigned short* __restrict__ dst,
    float* __restrict__ gsum, float* __restrict__ gss) {
  const int F = 256;
  const int bid = blockIdx.x;
  const int qi = (bid & 7) >> 1;                // channel quarter, pinned per XCD pair
  const int xb = (bid >> 3) * 2 + (bid & 1);    // node-block within quarter
  const int grp = threadIdx.x >> 3;             // 32 groups
  const int l   = threadIdx.x & 7;
  const int c0  = qi * 64 + l * 8;              // global channel base
  float bb[8], cc[8];
#pragma unroll
  for (int j = 0; j < 8; j++) { bb[j] = b[c0 + j]; cc[j] = cvec[c0 + j]; }
  const int base_n = xb * 128 + grp * 4;
  int begs[4], ends[4];
#pragma unroll
  for (int i = 0; i < 4; i++) {
    int n = base_n + i;
    begs[i] = (n < N_NODES) ? nptr[n] : 0;
    ends[i] = (n < N_NODES) ? nptr[n + 1] : 0;
  }
  int e[4][4];
#pragma unroll
  for (int i = 0; i < 4; i++) {
#pragma unroll
    for (int k = 0; k < 4; k++)
      e[i][k] = (begs[i] < ends[i]) ? nhes[min(begs[i] + k, ends[i] - 1)] : 0;
  }
  R4 r0, r1, r2, r3;                            // 16 row loads in flight
  load4(he, e[0], F, c0, r0);
  load4(he, e[1], F, c0, r1);
  load4(he, e[2], F, c0, r2);
  load4(he, e[3], F, c0, r3);
  __builtin_amdgcn_sched_barrier(0);            // pin: issue all before consume
  float sb[8] = {}, ssb[8] = {};
#pragma unroll
  for (int t = 0; t < 4; t++) {
    const int d = ends[t] - begs[t];
    float a[8] = {};
    const R4& rr = (t == 0) ? r0 : (t == 1) ? r1 : (t == 2) ? r2 : r3;
    accm4(rr, d, a);
    for (int j = begs[t] + 4; j < ends[t]; j += 4) {   // tail deg>4 (rare)
      int et[4];
#pragma unroll
      for (int k = 0; k < 4; k++) et[k] = nhes[min(j + k, ends[t] - 1)];
      R4 tt; load4(he, et, F, c0, tt);
      accm4(tt, ends[t] - j, a);
    }
    const int n = base_n + t;
    if (n < N_NODES) {
      float inv  = (d > 0) ? 1.0f / (float)d : 0.0f;
      float cmul = (d > 0) ? 1.0f : 0.0f;       // deg-0 node: +b only
      float o[8];
#pragma unroll
      for (int j = 0; j < 8; j++) {
        o[j] = fmaxf(fmaf(a[j], inv, bb[j] + cmul * cc[j]), 0.f);
        sb[j] += o[j]; ssb[j] += o[j] * o[j];
      }
      uintx4 ov;
      ov.x = pack2(o[0], o[1]); ov.y = pack2(o[2], o[3]);
      ov.z = pack2(o[4], o[5]); ov.w = pack2(o[6], o[7]);
      __builtin_nontemporal_store(ov, (uintx4*)(dst + (size_t)n * F + c0));
    }
  }
  __shared__ float Ls[32][64];
  __shared__ float Lss[32][64];
#pragma unroll
  for (int j = 0; j < 8; j++) { Ls[grp][l * 8 + j] = sb[j]; Lss[grp][l * 8 + j] = ssb[j]; }
  __syncthreads();
  if (threadIdx.x < 64) {
    int c = threadIdx.x;
    float a1 = 0.f, a2 = 0.f;
#pragma unroll
    for (int h = 0; h < 32; h++) { a1 += Ls[h][c]; a2 += Lss[h][c]; }
    const int rep = xb & (NREP - 1);
    atomicAdd(gsum + rep * 256 + qi * 64 + c, a1);
    atomicAdd(gss  + rep * 256 + qi * 64 + c, a2);
  }
}

// final hyperedge -> node, F=128, CHANNEL-HALVED + XCD-PINNED: half =
// (bid&7)>>2 -> each XCD pinned to one 3.85 MB half of HEb3 (fits L2).
__global__ __launch_bounds__(256, 4) void agg_out(
    const unsigned short* __restrict__ he, const int* __restrict__ nptr,
    const int* __restrict__ nhes, const float* __restrict__ b,
    const float* __restrict__ cvec, float* __restrict__ out) {
  const int F = 128;
  const int bid = blockIdx.x;
  const int hi = (bid & 7) >> 2;                // channel half, pinned per XCD quad
  const int xb = (bid >> 3) * 4 + (bid & 3);    // node-block within half
  const int grp = threadIdx.x >> 3;
  const int l   = threadIdx.x & 7;
  const int c0  = hi * 64 + l * 8;
  float bb[8], cc[8];
#pragma unroll
  for (int j = 0; j < 8; j++) { bb[j] = b[c0 + j]; cc[j] = cvec[c0 + j]; }
  const int base_n = xb * 128 + grp * 4;
  int begs[4], ends[4];
#pragma unroll
  for (int i = 0; i < 4; i++) {
    int n = base_n + i;
    begs[i] = (n < N_NODES) ? nptr[n] : 0;
    ends[i] = (n < N_NODES) ? nptr[n + 1] : 0;
  }
  int e[4][4];
#pragma unroll
  for (int i = 0; i < 4; i++) {
#pragma unroll
    for (int k = 0; k < 4; k++)
      e[i][k] = (begs[i] < ends[i]) ? nhes[min(begs[i] + k, ends[i] - 1)] : 0;
  }
  R4 r0, r1, r2, r3;
  load4(he, e[0], F, c0, r0);
  load4(he, e[1], F, c0, r1);
  load4(he, e[2], F, c0, r2);
  load4(he, e[3], F, c0, r3);
  __builtin_amdgcn_sched_barrier(0);            // pin: issue all before consume
#pragma unroll
  for (int t = 0; t < 4; t++) {
    const int d = ends[t] - begs[t];
    float a[8] = {};
    const R4& rr = (t == 0) ? r0 : (t == 1) ? r1 : (t == 2) ? r2 : r3;
    accm4(rr, d, a);
    for (int j = begs[t] + 4; j < ends[t]; j += 4) {
      int et[4];
#pragma unroll
      for (int k = 0; k < 4; k++) et[k] = nhes[min(j + k, ends[t] - 1)];
      R4 tt; load4(he, et, F, c0, tt);
      accm4(tt, ends[t] - j, a);
    }
    const int n = base_n + t;
    if (n < N_NODES) {
      float inv  = (d > 0) ? 1.0f / (float)d : 0.0f;
      float cmul = (d > 0) ? 1.0f : 0.0f;
      floatx4 o0, o1;
#pragma unroll
      for (int j = 0; j < 4; j++)
        o0[j] = fmaxf(fmaf(a[j], inv, bb[j] + cmul * cc[j]), 0.f);
#pragma unroll
      for (int j = 0; j < 4; j++)
        o1[j] = fmaxf(fmaf(a[4 + j], inv, bb[4 + j] + cmul * cc[4 + j]), 0.f);
      float* dp = out + (size_t)n * F + c0;
      __builtin_nontemporal_store(o0, (floatx4*)dp);
      __builtin_nontemporal_store(o1, (floatx4*)(dp + 4));
    }
  }
}

// ---------------------------------------------------------------- launch

extern "C" void kernel_launch(void* const* d_in, const int* in_sizes, int n_in,
                              void* d_out, int out_size, void* d_ws, size_t ws_size,
                              hipStream_t stream) {
  const float* x    = (const float*)d_in[0];
  const int*   edge = (const int*)d_in[1];
  const int*   nidx = edge;
  const int*   hidx = edge + N_INC;
  const float* W1  = (const float*)d_in[2];
  const float* b1  = (const float*)d_in[3];
  const float* g1  = (const float*)d_in[4];
  const float* be1 = (const float*)d_in[5];
  const float* W2  = (const float*)d_in[6];
  const float* b2  = (const float*)d_in[7];
  const float* g2  = (const float*)d_in[8];
  const float* be2 = (const float*)d_in[9];
  const float* W3  = (const float*)d_in[10];
  const float* b3  = (const float*)d_in[11];
  float* out = (float*)d_out;

  char* ws = (char*)d_ws;
  size_t off = 0;
  auto alloc = [&](size_t bytes) -> void* {
    void* p = ws + off;
    off = (off + bytes + 255) & ~(size_t)255;
    return p;
  };
  unsigned short* Xb   = (unsigned short*)alloc((size_t)N_NODES * 128 * 2);
  unsigned short* Bb   = (unsigned short*)alloc((size_t)N_NODES * 256 * 2);
  unsigned short* Hraw = (unsigned short*)alloc((size_t)HEPAD * 256 * 2);
  unsigned short* HEb  = (unsigned short*)alloc((size_t)HEPAD * 256 * 2);
  unsigned short* W1T  = (unsigned short*)alloc((size_t)256 * 128 * 2);
  unsigned short* W2T  = (unsigned short*)alloc((size_t)256 * 256 * 2);
  unsigned short* W3T  = (unsigned short*)alloc((size_t)128 * 256 * 2);
  size_t zero_begin = off;
  int* cnt = (int*)alloc((size_t)NTOT * 4);       // [he_cnt | node_cnt] contiguous
  float* gsum1 = (float*)alloc((size_t)NREP * 256 * 4);
  float* gss1  = (float*)alloc((size_t)NREP * 256 * 4);
  float* gsum2 = (float*)alloc((size_t)NREP * 256 * 4);
  float* gss2  = (float*)alloc((size_t)NREP * 256 * 4);
  float* c1 = (float*)alloc(1024);
  float* c2 = (float*)alloc(1024);
  float* c3 = (float*)alloc(1024);
  size_t zero_end = off;
  int* he_ptr    = (int*)alloc((size_t)(N_HE + 1) * 4);
  int* node_ptr  = (int*)alloc((size_t)(N_NODES + 1) * 4);
  int* he_fill   = (int*)alloc((size_t)N_HE * 4);
  int* node_fill = (int*)alloc((size_t)N_NODES * 4);
  int* he_nodes  = (int*)alloc((size_t)N_INC * 4);
  int* node_hes  = (int*)alloc((size_t)N_INC * 4);
  int* incl      = (int*)alloc((size_t)NTOT * 4);
  int* bsums     = (int*)alloc(512);

  // ---- zero counters/accumulators (single async memset) ----
  hipMemsetAsync((void*)(ws + zero_begin), 0, zero_end - zero_begin, stream);

  // ---- CSR build (combined scan) + x conversion + W1 fold (all fused) ----
  const int NCONV = (N_NODES * 16) / 256;   // 6250
  count_convert<<<NCONV + 8, 256, 0, stream>>>(nidx, hidx, cnt, x, Xb, W1, W1T, NCONV);
  {
    int nb = (NTOT + 1023) / 1024;      // 127
    scan1<<<nb, 1024, 0, stream>>>(cnt, incl, bsums, NTOT);
    scan2<<<1, 128, 0, stream>>>(bsums, nb);
    scan3c<<<nb, 1024, 0, stream>>>(cnt, incl, bsums, he_ptr, he_fill, node_ptr, node_fill);
  }
  fill_kernel<<<(N_INC + 255) / 256, 256, 0, stream>>>(nidx, hidx, node_fill, he_fill,
                                                       node_hes, he_nodes);

  const int MBHE = HEPAD / 128;         // 235
  const int QB = (N_NODES + 127) / 128; // 782 node-blocks (even)
  const int GRID_NA = 8 * ((QB + 1) / 2);   // 4 quarters x 2 XCDs each
  const int GRID_AO = 8 * ((QB + 3) / 4);   // 2 halves x 4 XCDs each
  const float invN = 1.0f / (float)N_NODES;

  // ---- layer 1 ----
  agg_he<<<(N_HE + 15) / 16, 256, 0, stream>>>(Xb, he_ptr, he_nodes, Hraw, 128, 4, N_HE);
  { dim3 g(MBHE, 2); gemm_mfma<<<g, 256, 0, stream>>>(Hraw, W1T, HEb, 128, 256); }
  node_agg_bn<<<GRID_NA, 256, 0, stream>>>(HEb, node_ptr, node_hes, b1, c1,
                                           Bb, gsum1, gss1);

  // ---- layer 2 ----
  { dim3 g(256 / 16, 1);
    fold_w<<<g, 256, 0, stream>>>(W2, gsum1, gss1, g1, be1, W2T, c2, 256, 256, invN); }
  agg_he<<<(N_HE + 7) / 8, 256, 0, stream>>>(Bb, he_ptr, he_nodes, Hraw, 256, 5, N_HE);
  { dim3 g(MBHE, 2); gemm_mfma<<<g, 256, 0, stream>>>(Hraw, W2T, HEb, 256, 256); }
  node_agg_bn<<<GRID_NA, 256, 0, stream>>>(HEb, node_ptr, node_hes, b2, c2,
                                           Bb, gsum2, gss2);

  // ---- layer 3 ----
  { dim3 g(256 / 16, 1);
    fold_w<<<g, 256, 0, stream>>>(W3, gsum2, gss2, g2, be2, W3T, c3, 256, 128, invN); }
  agg_he<<<(N_HE + 7) / 8, 256, 0, stream>>>(Bb, he_ptr, he_nodes, Hraw, 256, 5, N_HE);
  { dim3 g(MBHE, 1); gemm_mfma<<<g, 256, 0, stream>>>(Hraw, W3T, HEb, 256, 128); }
  agg_out<<<GRID_AO, 256, 0, stream>>>(HEb, node_ptr, node_hes, b3, c3, out);
}